// Round 1
// baseline (817.931 us; speedup 1.0000x reference)
//
#include <hip/hip_runtime.h>
#include <cfloat>

// KmeansVectorQuantizer: B=8, T=2048, G=8, D=64, V=1024
// Outputs (flat f32): ids[B*T*G], quantized_st[B*T*G*D], kmeans, commit, total
#define G_ 8
#define D_ 64
#define V_ 1024
#define BT_ 16384          // B*T
#define NTILES_ (BT_/64)   // 256

// ws layout: float ws[0]=loss_sum, ws[1]=denom ; csq at byte offset 256 (V*G floats)

__global__ void csq_kernel(const float* __restrict__ cb, float* __restrict__ csq) {
    int idx = blockIdx.x * blockDim.x + threadIdx.x;   // flat (v*G+g)
    if (idx >= V_ * G_) return;
    const float4* r = (const float4*)(cb + (size_t)idx * D_);
    float s = 0.f;
#pragma unroll
    for (int i = 0; i < D_ / 4; ++i) {
        float4 c = r[i];
        s += c.x * c.x + c.y * c.y + c.z * c.z + c.w * c.w;
    }
    csq[idx] = s;
}

__global__ __launch_bounds__(64) void vq_main(const float* __restrict__ inp,
                                              const int* __restrict__ pad,
                                              const float* __restrict__ cb,
                                              const float* __restrict__ csq,
                                              float* __restrict__ out_ids,
                                              float* __restrict__ out_q,
                                              float* __restrict__ ws) {
    const int lane = threadIdx.x;        // 0..63
    const int tile = blockIdx.x;         // 0..255
    const int g    = blockIdx.y;         // 0..7  (wave-uniform!)
    const int tok  = tile * 64 + lane;   // < BT_

    const float m = (pad[tok] == 0) ? 1.f : 0.f;

    // lane's x row: 64 floats, 256B contiguous & aligned
    const float4* xr = (const float4*)(inp + (size_t)tok * (G_ * D_) + g * D_);
    float4 x[16];
#pragma unroll
    for (int i = 0; i < 16; ++i) x[i] = xr[i];

    float best  = FLT_MAX;
    int   bestv = 0;
#pragma unroll 2
    for (int v = 0; v < V_; ++v) {
        // wave-uniform codebook row -> scalar loads
        const float4* cr = (const float4*)(cb + ((size_t)v * G_ + g) * D_);
        float a0 = 0.f, a1 = 0.f, a2 = 0.f, a3 = 0.f;
#pragma unroll
        for (int i = 0; i < 16; ++i) {
            float4 c = cr[i];
            a0 = fmaf(x[i].x, c.x, a0);
            a1 = fmaf(x[i].y, c.y, a1);
            a2 = fmaf(x[i].z, c.z, a2);
            a3 = fmaf(x[i].w, c.w, a3);
        }
        float dot  = (a0 + a1) + (a2 + a3);
        float dist = csq[v * G_ + g] - 2.f * dot;
        if (dist < best) { best = dist; bestv = v; }   // strict '<' keeps first index (matches argmin)
    }

    // gather the winning codeword, write quantized*mask, accumulate loss
    const float4* cr = (const float4*)(cb + ((size_t)bestv * G_ + g) * D_);
    float4* qout = (float4*)(out_q + (size_t)tok * (G_ * D_) + g * D_);
    float l = 0.f;
#pragma unroll
    for (int i = 0; i < 16; ++i) {
        float4 c = cr[i];
        float dx = c.x - x[i].x;
        float dy = c.y - x[i].y;
        float dz = c.z - x[i].z;
        float dw = c.w - x[i].w;
        l += dx * dx + dy * dy + dz * dz + dw * dw;
        float4 o;
        o.x = m * c.x; o.y = m * c.y; o.z = m * c.z; o.w = m * c.w;
        qout[i] = o;
    }
    l *= m;

    out_ids[(size_t)tok * G_ + g] = (m != 0.f) ? (float)bestv : -1.0f;

    // wave-level reductions (wave = 64 lanes)
#pragma unroll
    for (int off = 32; off > 0; off >>= 1) l += __shfl_down(l, off, 64);
    if (lane == 0) atomicAdd(&ws[0], l);

    if (g == 0) {   // count each token once for the denominator
        float mm = m;
#pragma unroll
        for (int off = 32; off > 0; off >>= 1) mm += __shfl_down(mm, off, 64);
        if (lane == 0) atomicAdd(&ws[1], mm);
    }
}

__global__ void finalize_kernel(const float* __restrict__ ws, float* __restrict__ out_losses) {
    float s = ws[0];
    float d = ws[1];
    float k = s / d;
    out_losses[0] = k;        // kmeans_loss
    out_losses[1] = k;        // commitment_loss (same value)
    out_losses[2] = 2.f * k;  // total (BETA=1)
}

extern "C" void kernel_launch(void* const* d_in, const int* in_sizes, int n_in,
                              void* d_out, int out_size, void* d_ws, size_t ws_size,
                              hipStream_t stream) {
    const float* inp = (const float*)d_in[0];   // (8,2048,512) f32
    const int*   pad = (const int*)d_in[1];     // (8,2048) i32
    const float* cb  = (const float*)d_in[2];   // (1024,8,64) f32

    float* out   = (float*)d_out;
    float* o_ids = out;                              // B*T*G
    float* o_q   = out + (size_t)BT_ * G_;           // B*T*G*D
    float* o_ls  = o_q + (size_t)BT_ * G_ * D_;      // 3 scalars

    float* ws  = (float*)d_ws;
    float* csq = (float*)((char*)d_ws + 256);

    hipMemsetAsync(d_ws, 0, 256, stream);

    csq_kernel<<<dim3((V_ * G_ + 255) / 256), dim3(256), 0, stream>>>(cb, csq);

    dim3 grid(NTILES_, G_);
    vq_main<<<grid, dim3(64), 0, stream>>>(inp, pad, cb, csq, o_ids, o_q, ws);

    finalize_kernel<<<1, 1, 0, stream>>>(ws, o_ls);
}

// Round 2
// 677.520 us; speedup vs baseline: 1.2072x; 1.2072x over previous
//
#include <hip/hip_runtime.h>
#include <cfloat>
#include <stdint.h>

// KmeansVectorQuantizer: B=8, T=2048, G=8, D=64, V=1024
// Outputs (flat f32): ids[B*T*G], quantized_st[B*T*G*D], kmeans, commit, total
#define G_ 8
#define D_ 64
#define V_ 1024
#define BT_ 16384
#define TPB_ 256
#define TILES_ (BT_ / TPB_)      // 64 worst-case tiles of active tokens
#define CHUNK_ 64                // codebook rows staged per LDS chunk
#define NCHUNK_ (V_ / CHUNK_)    // 16

// ws layout (bytes):
//   [0..3]          float loss_sum
//   [8..11]         int   nactive
//   [256 ..)        float csq[V_*G_]            (32 KB)
//   [33024 ..)      int   list[BT_]             (64 KB)

typedef uint32_t u32;

__global__ void csq_kernel(const float* __restrict__ cb, float* __restrict__ csq) {
    int idx = blockIdx.x * blockDim.x + threadIdx.x;   // flat (v*G+g)
    if (idx >= V_ * G_) return;
    const float4* r = (const float4*)(cb + (size_t)idx * D_);
    float s = 0.f;
#pragma unroll
    for (int i = 0; i < D_ / 4; ++i) {
        float4 c = r[i];
        s += c.x * c.x + c.y * c.y + c.z * c.z + c.w * c.w;
    }
    csq[idx] = s;
}

// One thread per token: append active tokens to list; finalize padded outputs.
__global__ void prep_kernel(const int* __restrict__ pad,
                            float* __restrict__ out_ids,
                            float* __restrict__ out_q,
                            int* __restrict__ cnt,
                            int* __restrict__ list) {
    int tok = blockIdx.x * blockDim.x + threadIdx.x;
    if (tok >= BT_) return;
    if (pad[tok] == 0) {
        int pos = atomicAdd(cnt, 1);       // compiler wave-coalesces this
        list[pos] = tok;
    } else {
        for (int g = 0; g < G_; ++g) out_ids[(size_t)tok * G_ + g] = -1.0f;
        float4 z = make_float4(0.f, 0.f, 0.f, 0.f);
        float4* q = (float4*)(out_q + (size_t)tok * (G_ * D_));
        for (int i = 0; i < G_ * D_ / 4; ++i) q[i] = z;
    }
}

__global__ __launch_bounds__(TPB_, 4) void vq_main(
    const float* __restrict__ inp,
    const float* __restrict__ cb,
    const float* __restrict__ csq,
    const int* __restrict__ cnt,
    const int* __restrict__ list,
    float* __restrict__ out_ids,
    float* __restrict__ out_q,
    float* __restrict__ ws) {

    __shared__ __align__(16) float buf[2][CHUNK_ * D_];   // 2 x 16 KB
    __shared__ float csqs[2][CHUNK_];

    const int g    = blockIdx.y;
    const int tid  = threadIdx.x;
    const int nact = cnt[0];
    const int start = blockIdx.x * TPB_;
    if (start >= nact) return;           // uniform early-exit for idle tiles

    const int  pos   = start + tid;
    const bool valid = (pos < nact);
    const int  tok   = list[valid ? pos : 0];

    // lane's x row: 64 floats, contiguous 256 B
    const float4* xr = (const float4*)(inp + (size_t)tok * (G_ * D_) + g * D_);
    float4 x[16];
#pragma unroll
    for (int i = 0; i < 16; ++i) x[i] = xr[i];

    // stage codebook chunk -> LDS buf[b] via async global->LDS (16 B/lane/issue)
    // chunk image layout: row-major, 64 rows x 256 B
    auto stage = [&](int chunk, int b) {
#pragma unroll
        for (int j = 0; j < 4; ++j) {
            int off = j * 4096 + tid * 16;          // byte offset in chunk image
            int row = off >> 8;                     // 256 B per row
            int col = off & 255;
            const float* gsrc =
                cb + ((size_t)(chunk * CHUNK_ + row) * G_ + g) * D_ + (col >> 2);
            void* ldst = (void*)&buf[b][off >> 2];
            __builtin_amdgcn_global_load_lds(
                (const __attribute__((address_space(1))) u32*)gsrc,
                (__attribute__((address_space(3))) u32*)(uintptr_t)ldst,
                16, 0, 0);
        }
        if (tid < CHUNK_)
            csqs[b][tid] = csq[(size_t)(chunk * CHUNK_ + tid) * G_ + g];
    };

    stage(0, 0);
    __syncthreads();

    float best  = FLT_MAX;
    int   bestv = 0;
    int   cur   = 0;
    for (int k = 0; k < NCHUNK_; ++k) {
        if (k + 1 < NCHUNK_) stage(k + 1, cur ^ 1);
        const float4* brow = (const float4*)&buf[cur][0];
#pragma unroll 2
        for (int r = 0; r < CHUNK_; ++r) {
            const float4* cr = brow + r * 16;       // wave-uniform addr -> broadcast
            float a0 = 0.f, a1 = 0.f, a2 = 0.f, a3 = 0.f;
#pragma unroll
            for (int i = 0; i < 16; ++i) {
                float4 c = cr[i];
                a0 = fmaf(x[i].x, c.x, a0);
                a1 = fmaf(x[i].y, c.y, a1);
                a2 = fmaf(x[i].z, c.z, a2);
                a3 = fmaf(x[i].w, c.w, a3);
            }
            float dot  = (a0 + a1) + (a2 + a3);
            float dist = csqs[cur][r] - 2.f * dot;
            if (dist < best) { best = dist; bestv = k * CHUNK_ + r; }  // first-min tie-break
        }
        __syncthreads();     // drains staged loads (vmcnt) + protects buffer reuse
        cur ^= 1;
    }

    // epilogue: gather winning codeword, write q (mask=1 for active), loss
    float l = 0.f;
    if (valid) {
        const float4* cr = (const float4*)(cb + ((size_t)bestv * G_ + g) * D_);
        float4* qout = (float4*)(out_q + (size_t)tok * (G_ * D_) + g * D_);
#pragma unroll
        for (int i = 0; i < 16; ++i) {
            float4 c = cr[i];
            float dx = c.x - x[i].x, dy = c.y - x[i].y;
            float dz = c.z - x[i].z, dw = c.w - x[i].w;
            l += dx * dx + dy * dy + dz * dz + dw * dw;
            qout[i] = c;
        }
        out_ids[(size_t)tok * G_ + g] = (float)bestv;
    }

#pragma unroll
    for (int off = 32; off > 0; off >>= 1) l += __shfl_down(l, off, 64);
    if ((tid & 63) == 0) atomicAdd(&ws[0], l);
}

__global__ void finalize_kernel(const float* __restrict__ ws,
                                const int* __restrict__ cnt,
                                float* __restrict__ out_losses) {
    float k = ws[0] / (float)cnt[0];
    out_losses[0] = k;        // kmeans_loss
    out_losses[1] = k;        // commitment_loss (numerically identical)
    out_losses[2] = 2.f * k;  // total (BETA=1)
}

extern "C" void kernel_launch(void* const* d_in, const int* in_sizes, int n_in,
                              void* d_out, int out_size, void* d_ws, size_t ws_size,
                              hipStream_t stream) {
    const float* inp = (const float*)d_in[0];   // (8,2048,512) f32
    const int*   pad = (const int*)d_in[1];     // (8,2048) i32
    const float* cb  = (const float*)d_in[2];   // (1024,8,64) f32

    float* out   = (float*)d_out;
    float* o_ids = out;                              // B*T*G
    float* o_q   = out + (size_t)BT_ * G_;           // B*T*G*D
    float* o_ls  = o_q + (size_t)BT_ * G_ * D_;      // 3 scalars

    float* ws   = (float*)d_ws;
    int*   cnt  = (int*)((char*)d_ws + 8);
    float* csq  = (float*)((char*)d_ws + 256);
    int*   list = (int*)((char*)d_ws + 256 + 32768);

    hipMemsetAsync(d_ws, 0, 256, stream);

    csq_kernel<<<dim3((V_ * G_ + 255) / 256), dim3(256), 0, stream>>>(cb, csq);
    prep_kernel<<<dim3(BT_ / 256), dim3(256), 0, stream>>>(pad, o_ids, o_q, cnt, list);

    dim3 grid(TILES_, G_);
    vq_main<<<grid, dim3(TPB_), 0, stream>>>(inp, cb, csq, cnt, list, o_ids, o_q, ws);

    finalize_kernel<<<1, 1, 0, stream>>>(ws, cnt, o_ls);
}

// Round 3
// 297.553 us; speedup vs baseline: 2.7489x; 2.2770x over previous
//
#include <hip/hip_runtime.h>
#include <cfloat>
#include <stdint.h>

// KmeansVectorQuantizer: B=8, T=2048, G=8, D=64, V=1024
// Outputs (flat f32): ids[B*T*G], quantized_st[B*T*G*D], kmeans, commit, total
#define G_ 8
#define D_ 64
#define V_ 1024
#define BT_ 16384
#define NV_ 8                 // codebook splits (grid.z) for TLP
#define ROWS_ (V_ / NV_)      // 128 rows per split
#define TPB_ 256

typedef unsigned long long u64;
typedef uint32_t u32;

// ws layout (bytes):
//   [0..3]      float loss_sum
//   [8..11]     int   nactive
//   [256)       float csq[V_*G_]     32 KB
//   [33024)     int   list[BT_]      64 KB
//   [98560)     u64   cand[BT_*G_]    1 MB   (init 0xFF = u64 max)

__global__ void csq_kernel(const float* __restrict__ cb, float* __restrict__ csq) {
    int idx = blockIdx.x * blockDim.x + threadIdx.x;   // flat (v*G+g)
    if (idx >= V_ * G_) return;
    const float4* r = (const float4*)(cb + (size_t)idx * D_);
    float s = 0.f;
#pragma unroll
    for (int i = 0; i < D_ / 4; ++i) {
        float4 c = r[i];
        s += c.x * c.x + c.y * c.y + c.z * c.z + c.w * c.w;
    }
    csq[idx] = s;
}

// One thread per token: append active tokens; finalize padded outputs.
__global__ void prep_kernel(const int* __restrict__ pad,
                            float* __restrict__ out_ids,
                            float* __restrict__ out_q,
                            int* __restrict__ cnt,
                            int* __restrict__ list) {
    int tok = blockIdx.x * blockDim.x + threadIdx.x;
    if (tok >= BT_) return;
    if (pad[tok] == 0) {
        int pos = atomicAdd(cnt, 1);           // wave-coalesced by compiler
        list[pos] = tok;
    } else {
        for (int g = 0; g < G_; ++g) out_ids[(size_t)tok * G_ + g] = -1.0f;
        float4 z = make_float4(0.f, 0.f, 0.f, 0.f);
        float4* q = (float4*)(out_q + (size_t)tok * (G_ * D_));
        for (int i = 0; i < G_ * D_ / 4; ++i) q[i] = z;
    }
}

// Hot kernel: one token per lane (x resident in 64 VGPRs); codebook rows come
// in through SGPRs (s_load, wave-uniform address) -> v_fmac vD, sC, vX.
// No LDS, no VMEM in the inner loop.
__global__ __launch_bounds__(TPB_, 6) void vq_scan(
    const float* __restrict__ inp,
    const float* __restrict__ cb,
    const float* __restrict__ csq,
    const int* __restrict__ cnt,
    const int* __restrict__ list,
    u64* __restrict__ cand) {

    const int nact  = cnt[0];
    const int start = blockIdx.x * TPB_;
    if (start >= nact) return;                 // uniform early-exit

    const int  tid   = threadIdx.x;
    const int  g     = blockIdx.y;             // wave-uniform
    const int  s     = blockIdx.z;             // codebook split
    const int  pos   = start + tid;
    const bool valid = (pos < nact);
    const int  tok   = list[valid ? pos : 0];

    const float4* xr = (const float4*)(inp + (size_t)tok * (G_ * D_) + g * D_);
    float4 x[16];
#pragma unroll
    for (int i = 0; i < 16; ++i) x[i] = xr[i];

    float best  = FLT_MAX;
    int   bestv = 0;
    const int v0 = s * ROWS_;
    for (int r = 0; r < ROWS_; ++r) {
        const int v = v0 + r;
        // force the address math into SGPRs so the row loads scalarize
        const int roff = __builtin_amdgcn_readfirstlane((v * G_ + g) * D_);
        const float4* cr = (const float4*)(cb + roff);
        const float cs = csq[__builtin_amdgcn_readfirstlane(v * G_ + g)];
        float a0 = 0.f, a1 = 0.f, a2 = 0.f, a3 = 0.f;
#pragma unroll
        for (int i = 0; i < 16; ++i) {
            float4 c = cr[i];
            a0 = fmaf(x[i].x, c.x, a0);
            a1 = fmaf(x[i].y, c.y, a1);
            a2 = fmaf(x[i].z, c.z, a2);
            a3 = fmaf(x[i].w, c.w, a3);
        }
        float dot  = (a0 + a1) + (a2 + a3);
        float dist = cs - 2.f * dot;
        if (dist < best) { best = dist; bestv = v; }   // strict '<': first-min
    }

    if (valid) {
        // sortable encode: (dist, id) -> u64, atomicMin == (min dist, then min id)
        u32 u = __float_as_uint(best);
        u = u ^ ((u >> 31) ? 0xFFFFFFFFu : 0x80000000u);
        u64 c = ((u64)u << 32) | (u32)bestv;
        atomicMin(&cand[(size_t)pos * G_ + g], c);
    }
}

// Epilogue: decode winner, gather codeword, write q/ids, accumulate loss.
__global__ void vq_merge(const float* __restrict__ inp,
                         const float* __restrict__ cb,
                         const int* __restrict__ cnt,
                         const int* __restrict__ list,
                         const u64* __restrict__ cand,
                         float* __restrict__ out_ids,
                         float* __restrict__ out_q,
                         float* __restrict__ ws) {
    const int nact = cnt[0];
    const int idx  = blockIdx.x * blockDim.x + threadIdx.x;  // = pos*G_+g
    float l = 0.f;
    if (idx < nact * G_) {
        const int g   = idx & (G_ - 1);
        const int pos = idx >> 3;
        const int tok = list[pos];
        const int bestv = (int)(cand[idx] & 0xFFFFFFFFull);
        const float4* cr = (const float4*)(cb + ((size_t)bestv * G_ + g) * D_);
        const float4* xr = (const float4*)(inp + (size_t)tok * (G_ * D_) + g * D_);
        float4* qout = (float4*)(out_q + (size_t)tok * (G_ * D_) + g * D_);
#pragma unroll
        for (int i = 0; i < 16; ++i) {
            float4 c = cr[i], xx = xr[i];
            float dx = c.x - xx.x, dy = c.y - xx.y;
            float dz = c.z - xx.z, dw = c.w - xx.w;
            l += dx * dx + dy * dy + dz * dz + dw * dw;
            qout[i] = c;
        }
        out_ids[(size_t)tok * G_ + g] = (float)bestv;
    }
#pragma unroll
    for (int off = 32; off > 0; off >>= 1) l += __shfl_down(l, off, 64);
    if ((threadIdx.x & 63) == 0) atomicAdd(&ws[0], l);
}

__global__ void finalize_kernel(const float* __restrict__ ws,
                                const int* __restrict__ cnt,
                                float* __restrict__ out_losses) {
    float k = ws[0] / (float)cnt[0];
    out_losses[0] = k;        // kmeans_loss
    out_losses[1] = k;        // commitment_loss (numerically identical)
    out_losses[2] = 2.f * k;  // total (BETA=1)
}

extern "C" void kernel_launch(void* const* d_in, const int* in_sizes, int n_in,
                              void* d_out, int out_size, void* d_ws, size_t ws_size,
                              hipStream_t stream) {
    const float* inp = (const float*)d_in[0];   // (8,2048,512) f32
    const int*   pad = (const int*)d_in[1];     // (8,2048) i32
    const float* cb  = (const float*)d_in[2];   // (1024,8,64) f32

    float* out   = (float*)d_out;
    float* o_ids = out;                              // B*T*G
    float* o_q   = out + (size_t)BT_ * G_;           // B*T*G*D
    float* o_ls  = o_q + (size_t)BT_ * G_ * D_;      // 3 scalars

    float* ws   = (float*)d_ws;
    int*   cnt  = (int*)((char*)d_ws + 8);
    float* csq  = (float*)((char*)d_ws + 256);
    int*   list = (int*)((char*)d_ws + 33024);
    u64*   cand = (u64*)((char*)d_ws + 98560);

    hipMemsetAsync(d_ws, 0, 256, stream);
    hipMemsetAsync(cand, 0xFF, (size_t)BT_ * G_ * sizeof(u64), stream);

    csq_kernel<<<dim3((V_ * G_ + 255) / 256), dim3(256), 0, stream>>>(cb, csq);
    prep_kernel<<<dim3(BT_ / 256), dim3(256), 0, stream>>>(pad, o_ids, o_q, cnt, list);

    dim3 grid(BT_ / TPB_, G_, NV_);                  // worst-case tiles x g x split
    vq_scan<<<grid, dim3(TPB_), 0, stream>>>(inp, cb, csq, cnt, list, cand);

    vq_merge<<<dim3((BT_ * G_ + 255) / 256), dim3(256), 0, stream>>>(
        inp, cb, cnt, list, cand, o_ids, o_q, ws);

    finalize_kernel<<<1, 1, 0, stream>>>(ws, cnt, o_ls);
}